// Round 11
// baseline (168.859 us; speedup 1.0000x reference)
//
#include <hip/hip_runtime.h>
#include <stdint.h>

#define Bn 2048
#define Dn 1024
#define Hn 2048
#define On 512
#define En 8

typedef __bf16 bf16x8 __attribute__((ext_vector_type(8)));
typedef float f32x4 __attribute__((ext_vector_type(4)));
typedef unsigned short ushort_t;
typedef ushort_t ushort4v __attribute__((ext_vector_type(4)));

__device__ __forceinline__ ushort_t f2bf(float v) {
  union { float f; uint32_t u; } a; a.f = v;
  uint32_t u = a.u;
  return (ushort_t)((u + 0x7fffu + ((u >> 16) & 1u)) >> 16);  // RNE, finite inputs
}

__device__ __forceinline__ void gload16(const void* g, void* l) {
  __builtin_amdgcn_global_load_lds((const uint32_t*)g, (uint32_t*)l, 16, 0, 0);
}

// ---------------- init: zero counts/cursors every launch (determinism) ----------------
__global__ void init_kernel(int* counts, int* cursors) {
  int t = threadIdx.x;
  if (t < En) { counts[t] = 0; cursors[t] = 0; }
}

// ================= fused prep: gating+x-cast | tcast fc1_w | tcast fc2_w =================
#define NB_G (Bn / 8)
#define NB_T1 ((Dn / 64) * (Hn / 64) * En)
#define NB_T2 ((Hn / 64) * (On / 64) * En)

__device__ __forceinline__ void tcast64(const float* __restrict__ inp, ushort_t* __restrict__ outp,
                                        int R, int C, int r0, int c0, float* tile /*64x65*/) {
  int t = threadIdx.x;
  int rr = t >> 4;          // 0..15
  int cc4 = (t & 15) * 4;   // 0..60
#pragma unroll
  for (int j = 0; j < 4; j++) {
    float4 v = *(const float4*)&inp[(size_t)(r0 + j * 16 + rr) * C + c0 + cc4];
    float* tp = &tile[(j * 16 + rr) * 65 + cc4];
    tp[0] = v.x; tp[1] = v.y; tp[2] = v.z; tp[3] = v.w;
  }
  __syncthreads();
#pragma unroll
  for (int j = 0; j < 4; j++) {
    int c = j * 16 + rr;   // column of input = row of output
    ushort4v o;
    o[0] = f2bf(tile[(cc4 + 0) * 65 + c]);
    o[1] = f2bf(tile[(cc4 + 1) * 65 + c]);
    o[2] = f2bf(tile[(cc4 + 2) * 65 + c]);
    o[3] = f2bf(tile[(cc4 + 3) * 65 + c]);
    *(ushort4v*)&outp[(size_t)(c0 + c) * R + r0 + cc4] = o;
  }
}

__global__ __launch_bounds__(256) void prep_kernel(
    const float* __restrict__ x, const float* __restrict__ wg,
    const float* __restrict__ fc1w, const float* __restrict__ fc2w,
    ushort_t* __restrict__ x_bf, ushort_t* __restrict__ w1t, ushort_t* __restrict__ w2t,
    int* __restrict__ top_idx, float* __restrict__ gates, int* __restrict__ counts) {
  __shared__ float smem[En * Dn];  // 32 KB
  __shared__ int lcnt[En];
  int bid = blockIdx.x;
  int t = threadIdx.x;

  if (bid < NB_G) {
    float* wgs = smem;
    for (int i = t; i < Dn * En; i += 256) {
      int d = i >> 3, e = i & 7;
      wgs[e * Dn + d] = wg[i];  // wg is [d][e]
    }
    if (t < En) lcnt[t] = 0;
    __syncthreads();
    int w = t >> 6, lane = t & 63;
#pragma unroll
    for (int r = 0; r < 2; r++) {
      int b = bid * 8 + w * 2 + r;
      const float* xr = x + (size_t)b * Dn;
      ushort_t* xo = x_bf + (size_t)b * Dn;
      float xv[16];
#pragma unroll
      for (int j = 0; j < 16; j++) xv[j] = xr[lane + j * 64];
      float acc[En];
#pragma unroll
      for (int e = 0; e < En; e++) acc[e] = 0.f;
#pragma unroll
      for (int j = 0; j < 16; j++) {
        int d = lane + j * 64;
        xo[d] = f2bf(xv[j]);
#pragma unroll
        for (int e = 0; e < En; e++) acc[e] += xv[j] * wgs[e * Dn + d];
      }
#pragma unroll
      for (int off = 32; off; off >>= 1) {
#pragma unroll
        for (int e = 0; e < En; e++) acc[e] += __shfl_down(acc[e], off);
      }
      if (lane == 0) {
        float best = -1e30f, second = -1e30f; int bi = 0, si = 0;
#pragma unroll
        for (int e = 0; e < En; e++) {
          float l = acc[e];
          if (l > best) { second = best; si = bi; best = l; bi = e; }
          else if (l > second) { second = l; si = e; }
        }
        float e1 = expf(second - best);
        float inv = 1.f / (1.f + e1);
        top_idx[2 * b] = bi; top_idx[2 * b + 1] = si;
        gates[2 * b] = inv;  gates[2 * b + 1] = e1 * inv;
        atomicAdd(&lcnt[bi], 1);
        atomicAdd(&lcnt[si], 1);
      }
    }
    __syncthreads();
    if (t < En) {
      int c = lcnt[t];
      if (c) atomicAdd(&counts[t], c);
    }
  } else if (bid < NB_G + NB_T1) {
    int idx = bid - NB_G;
    constexpr int TPE = (Dn / 64) * (Hn / 64);
    int z = idx / TPE, rem = idx % TPE;
    int r0 = (rem / (Hn / 64)) * 64, c0 = (rem % (Hn / 64)) * 64;
    tcast64(fc1w + (size_t)z * Dn * Hn, w1t + (size_t)z * Dn * Hn, Dn, Hn, r0, c0, smem);
  } else {
    int idx = bid - NB_G - NB_T1;
    constexpr int TPE = (Hn / 64) * (On / 64);
    int z = idx / TPE, rem = idx % TPE;
    int r0 = (rem / (On / 64)) * 64, c0 = (rem % (On / 64)) * 64;
    tcast64(fc2w + (size_t)z * Hn * On, w2t + (size_t)z * Hn * On, Hn, On, r0, c0, smem);
  }
}

// ---------------- offsets (exclusive prefix over 8 counts) ----------------
__global__ void offsets_kernel(const int* counts, int* offsets, int* cursors) {
  if (threadIdx.x == 0) {
    int s = 0;
    for (int e = 0; e < En; e++) { offsets[e] = s; s += counts[e]; }
  }
  if (threadIdx.x < En) cursors[threadIdx.x] = 0;
}

// ---------------- assign rows to compact slots ----------------
__global__ void assign_kernel(const int* __restrict__ top_idx, const int* __restrict__ offsets,
                              int* cursors, int* __restrict__ s2r, int* __restrict__ r2s) {
  int b = blockIdx.x * 256 + threadIdx.x;
  if (b >= Bn) return;
#pragma unroll
  for (int k = 0; k < 2; k++) {
    int e = top_idx[2 * b + k];
    int pos = atomicAdd(&cursors[e], 1);
    int slot = offsets[e] + pos;
    s2r[slot] = b;
    r2s[2 * b + k] = slot;
  }
}

// ---- grouped GEMM: SINGLE-WAVE 64x64xBK64 blocks, mfma 16x16x32 bf16, barrier-free ----
// A: per-lane global->reg fragment loads (wave owns all 64 rows: no duplication).
// B: 8 KB LDS tile, T2 swizzle (linear-dest gload_lds + pre-swizzled source, rule #21).
// Staging: step i writes LDS rows i*8..i*8+7 -> dest ushort offset i*512 + lane*8
// (8 rows = 512 ushorts per step; r10 bug was i*1024 = OOB past 8 KB).
// No s_barrier: vmcnt(0) self-wait after own staging; lgkmcnt(0) before LDS reuse.
template <bool GATHER, bool FC1, int N, int K, int SPLITK>
__global__ __launch_bounds__(64, 4) void moe_gemm_kernel(
    const ushort_t* __restrict__ A, const ushort_t* __restrict__ WT,
    const float* __restrict__ bias, const int* __restrict__ offsets,
    const int* __restrict__ counts, const int* __restrict__ s2r,
    ushort_t* __restrict__ outH, float* __restrict__ outL, float* __restrict__ outL2) {
  constexpr int NBL = N / 64;
  constexpr int KS = K / SPLITK;
  constexpr int NT = KS / 64;
  int e = blockIdx.z;
  int cnt = counts[e];
  int rb = blockIdx.y;
  if (rb * 64 >= cnt) return;
  int base = offsets[e];
  int ks = blockIdx.x / NBL;
  int nb = (blockIdx.x % NBL) * 64;
  int k0 = ks * KS;
  __shared__ __align__(16) ushort_t Bs[64 * 64];  // 8 KB
  int lane = threadIdx.x;

  // B staging: step i covers rows i*8 + (lane>>3), slot lane&7 holds swizzled group
  int scol = ((lane & 7) ^ (lane >> 3)) * 8;  // pre-swizzled global column (elements)
  const ushort_t* bptr = WT + ((size_t)e * N + nb + (lane >> 3)) * K + k0 + scol;

  // A per-lane fragment row pointers (4 rows per lane), gathered for fc1
  int kg = (lane >> 4) * 8;
  const ushort_t* aP[4];
#pragma unroll
  for (int m = 0; m < 4; m++) {
    int lr = rb * 64 + m * 16 + (lane & 15);
    int lrc = lr < cnt ? lr : cnt - 1;
    int slot = base + lrc;
    int row = GATHER ? s2r[slot] : slot;
    aP[m] = A + (size_t)row * K + k0 + kg;
  }

  f32x4 zero = {0.f, 0.f, 0.f, 0.f};
  f32x4 acc[4][4];
#pragma unroll
  for (int m = 0; m < 4; m++)
#pragma unroll
    for (int n = 0; n < 4; n++) acc[m][n] = zero;

  int b_r = lane & 15;     // B fragment row base (n*16 added per frag)
  int axor = lane & 7;     // row&7 (row bases mult of 8/16 -> invariant)
  int c16 = lane >> 4;     // base 16B-slot index within row

  for (int kt = 0; kt < NT; kt++) {
    // stage B(kt): 8 x gload16, linear dest (8 rows = 512 ushorts per step)
#pragma unroll
    for (int i = 0; i < 8; i++)
      gload16(bptr + (size_t)i * 8 * K + kt * 64, &Bs[i * 512 + lane * 8]);
    // A frags for kk=0 (in flight with B staging)
    bf16x8 af0[4];
#pragma unroll
    for (int m = 0; m < 4; m++) af0[m] = *(const bf16x8*)(aP[m] + kt * 64);
    asm volatile("s_waitcnt vmcnt(0)" ::: "memory");  // B in LDS, af0 in regs
    __builtin_amdgcn_sched_barrier(0);
    // A frags for kk=1: latency hides under kk=0 MFMAs
    bf16x8 af1[4];
#pragma unroll
    for (int m = 0; m < 4; m++) af1[m] = *(const bf16x8*)(aP[m] + kt * 64 + 32);
    // kk = 0
    {
      bf16x8 bfr[4];
#pragma unroll
      for (int n = 0; n < 4; n++)
        bfr[n] = *(const bf16x8*)((const char*)Bs + (b_r + n * 16) * 128 +
                                  ((c16 ^ axor) << 4));
#pragma unroll
      for (int m = 0; m < 4; m++)
#pragma unroll
        for (int n = 0; n < 4; n++)
          acc[m][n] = __builtin_amdgcn_mfma_f32_16x16x32_bf16(af0[m], bfr[n], acc[m][n], 0, 0, 0);
    }
    // kk = 1
    {
      bf16x8 bfr[4];
#pragma unroll
      for (int n = 0; n < 4; n++)
        bfr[n] = *(const bf16x8*)((const char*)Bs + (b_r + n * 16) * 128 +
                                  (((4 + c16) ^ axor) << 4));
#pragma unroll
      for (int m = 0; m < 4; m++)
#pragma unroll
        for (int n = 0; n < 4; n++)
          acc[m][n] = __builtin_amdgcn_mfma_f32_16x16x32_bf16(af1[m], bfr[n], acc[m][n], 0, 0, 0);
    }
    asm volatile("s_waitcnt lgkmcnt(0)" ::: "memory");  // all ds_reads retired: LDS reusable
    __builtin_amdgcn_sched_barrier(0);
  }

  // epilogue: D layout col=lane&15, row=(lane>>4)*4+i
  float* dst = (SPLITK > 1 && ks > 0) ? (outL2 + (size_t)(ks - 1) * (2 * Bn * On)) : outL;
  int lr0 = rb * 64;
#pragma unroll
  for (int m = 0; m < 4; m++) {
#pragma unroll
    for (int i = 0; i < 4; i++) {
      int lr = lr0 + m * 16 + (lane >> 4) * 4 + i;
      if (lr < cnt) {
        int slot = base + lr;
#pragma unroll
        for (int n = 0; n < 4; n++) {
          int col = nb + n * 16 + (lane & 15);
          float v = acc[m][n][i] + (ks == 0 ? bias[e * N + col] : 0.f);
          if (FC1) {
            float g = 0.5f * v * (1.0f + erff(v * 0.70710678118654752f));
            outH[(size_t)slot * N + col] = f2bf(g);
          } else {
            dst[(size_t)slot * N + col] = v;
          }
        }
      }
    }
  }
}

// ---------------- combine: sum split-K partials, logsoftmax over O=512, weighted sum ----------------
__device__ __forceinline__ float blk_reduce(float v, bool ismax) {
  __shared__ float sbuf[4];
  int lane = threadIdx.x & 63, w = threadIdx.x >> 6;
#pragma unroll
  for (int off = 32; off; off >>= 1) {
    float o = __shfl_down(v, off);
    v = ismax ? fmaxf(v, o) : (v + o);
  }
  __syncthreads();
  if (lane == 0) sbuf[w] = v;
  __syncthreads();
  float r = sbuf[0];
#pragma unroll
  for (int i = 1; i < 4; i++) r = ismax ? fmaxf(r, sbuf[i]) : (r + sbuf[i]);
  return r;
}

__global__ void combine_kernel(const float* __restrict__ l2a, const float* __restrict__ l2b,
                               const int* __restrict__ r2s, const float* __restrict__ gates,
                               float* __restrict__ out) {
  int b = blockIdx.x, t = threadIdx.x;
  float c0 = 0.f, c1 = 0.f;
#pragma unroll
  for (int k = 0; k < 2; k++) {
    int slot = r2s[2 * b + k];
    float g = gates[2 * b + k];
    const float* lp0 = l2a + (size_t)slot * On;
    float v0 = lp0[t], v1 = lp0[t + 256];
#pragma unroll
    for (int p = 0; p < 3; p++) {
      const float* lpp = l2b + (size_t)p * (2 * Bn * On) + (size_t)slot * On;
      v0 += lpp[t];
      v1 += lpp[t + 256];
    }
    float m = blk_reduce(fmaxf(v0, v1), true);
    float s = blk_reduce(expf(v0 - m) + expf(v1 - m), false);
    float lse = m + logf(s);
    c0 += g * expf(v0 - lse);
    c1 += g * expf(v1 - lse);
  }
  const float EPSv = 2.220446049250313e-16f;
  out[(size_t)b * On + t] = logf(fmaxf(c0, EPSv));
  out[(size_t)b * On + t + 256] = logf(fmaxf(c1, EPSv));
}

extern "C" void kernel_launch(void* const* d_in, const int* in_sizes, int n_in,
                              void* d_out, int out_size, void* d_ws, size_t ws_size,
                              hipStream_t stream) {
  const float* x = (const float*)d_in[0];
  const float* wgate = (const float*)d_in[1];
  const float* fc1w = (const float*)d_in[2];
  const float* fc1b = (const float*)d_in[3];
  const float* fc2w = (const float*)d_in[4];
  const float* fc2b = (const float*)d_in[5];
  float* out = (float*)d_out;

  char* ws = (char*)d_ws;
  size_t o = 0;
  ushort_t* x_bf = (ushort_t*)(ws + o); o += (size_t)Bn * Dn * 2;        // 4 MB
  ushort_t* w1t  = (ushort_t*)(ws + o); o += (size_t)En * Hn * Dn * 2;   // 32 MB [E][H][D]
  ushort_t* w2t  = (ushort_t*)(ws + o); o += (size_t)En * On * Hn * 2;   // 16 MB [E][O][H]
  ushort_t* hbuf = (ushort_t*)(ws + o); o += (size_t)2 * Bn * Hn * 2;    // 16 MB [slot][H]
  float* l2buf   = (float*)(ws + o);    o += (size_t)2 * Bn * On * 4;    // 8 MB (split-K partial 0)
  int* top_idx   = (int*)(ws + o);      o += (size_t)Bn * 2 * 4;
  float* gates   = (float*)(ws + o);    o += (size_t)Bn * 2 * 4;
  int* r2s       = (int*)(ws + o);      o += (size_t)Bn * 2 * 4;
  int* s2r       = (int*)(ws + o);      o += (size_t)2 * Bn * 4;
  int* counts    = (int*)(ws + o);      o += 64;
  int* offsets   = (int*)(ws + o);      o += 64;
  int* cursors   = (int*)(ws + o);      o += 64;
  // split-K partials 1..3 (24 MB) alias w1t (32 MB): w1t is fully consumed by fc1
  // (completes before fc2 starts, same stream) and rewritten by prep each launch.
  float* l2buf1  = (float*)w1t;

  hipLaunchKernelGGL(init_kernel, dim3(1), dim3(64), 0, stream, counts, cursors);
  hipLaunchKernelGGL(prep_kernel, dim3(NB_G + NB_T1 + NB_T2), dim3(256), 0, stream,
                     x, wgate, fc1w, fc2w, x_bf, w1t, w2t, top_idx, gates, counts);
  hipLaunchKernelGGL(offsets_kernel, dim3(1), dim3(64), 0, stream, counts, offsets, cursors);
  hipLaunchKernelGGL(assign_kernel, dim3(Bn / 256), dim3(256), 0, stream,
                     top_idx, offsets, cursors, s2r, r2s);
  hipLaunchKernelGGL((moe_gemm_kernel<true, true, Hn, Dn, 1>), dim3(Hn / 64, 32, En), dim3(64),
                     0, stream, x_bf, w1t, fc1b, offsets, counts, s2r, hbuf, (float*)nullptr,
                     (float*)nullptr);
  hipLaunchKernelGGL((moe_gemm_kernel<false, false, On, Hn, 4>), dim3((On / 64) * 4, 32, En),
                     dim3(64), 0, stream, hbuf, w2t, fc2b, offsets, counts, s2r,
                     (ushort_t*)nullptr, l2buf, l2buf1);
  hipLaunchKernelGGL(combine_kernel, dim3(Bn), dim3(256), 0, stream, l2buf, l2buf1, r2s, gates, out);
}

// Round 12
// 130.095 us; speedup vs baseline: 1.2980x; 1.2980x over previous
//
#include <hip/hip_runtime.h>
#include <stdint.h>

#define Bn 2048
#define Dn 1024
#define Hn 2048
#define On 512
#define En 8

typedef __bf16 bf16x8 __attribute__((ext_vector_type(8)));
typedef float f32x4 __attribute__((ext_vector_type(4)));
typedef unsigned short ushort_t;
typedef ushort_t ushort4v __attribute__((ext_vector_type(4)));

__device__ __forceinline__ ushort_t f2bf(float v) {
  union { float f; uint32_t u; } a; a.f = v;
  uint32_t u = a.u;
  return (ushort_t)((u + 0x7fffu + ((u >> 16) & 1u)) >> 16);  // RNE, finite inputs
}

__device__ __forceinline__ void gload16(const void* g, void* l) {
  __builtin_amdgcn_global_load_lds((const uint32_t*)g, (uint32_t*)l, 16, 0, 0);
}

// ---------------- init: zero counts/cursors every launch (determinism) ----------------
__global__ void init_kernel(int* counts, int* cursors) {
  int t = threadIdx.x;
  if (t < En) { counts[t] = 0; cursors[t] = 0; }
}

// ================= fused prep: gating+x-cast | tcast fc1_w | tcast fc2_w =================
#define NB_G (Bn / 8)
#define NB_T1 ((Dn / 64) * (Hn / 64) * En)
#define NB_T2 ((Hn / 64) * (On / 64) * En)

__device__ __forceinline__ void tcast64(const float* __restrict__ inp, ushort_t* __restrict__ outp,
                                        int R, int C, int r0, int c0, float* tile /*64x65*/) {
  int t = threadIdx.x;
  int rr = t >> 4;          // 0..15
  int cc4 = (t & 15) * 4;   // 0..60
#pragma unroll
  for (int j = 0; j < 4; j++) {
    float4 v = *(const float4*)&inp[(size_t)(r0 + j * 16 + rr) * C + c0 + cc4];
    float* tp = &tile[(j * 16 + rr) * 65 + cc4];
    tp[0] = v.x; tp[1] = v.y; tp[2] = v.z; tp[3] = v.w;
  }
  __syncthreads();
#pragma unroll
  for (int j = 0; j < 4; j++) {
    int c = j * 16 + rr;   // column of input = row of output
    ushort4v o;
    o[0] = f2bf(tile[(cc4 + 0) * 65 + c]);
    o[1] = f2bf(tile[(cc4 + 1) * 65 + c]);
    o[2] = f2bf(tile[(cc4 + 2) * 65 + c]);
    o[3] = f2bf(tile[(cc4 + 3) * 65 + c]);
    *(ushort4v*)&outp[(size_t)(c0 + c) * R + r0 + cc4] = o;
  }
}

__global__ __launch_bounds__(256) void prep_kernel(
    const float* __restrict__ x, const float* __restrict__ wg,
    const float* __restrict__ fc1w, const float* __restrict__ fc2w,
    ushort_t* __restrict__ x_bf, ushort_t* __restrict__ w1t, ushort_t* __restrict__ w2t,
    int* __restrict__ top_idx, float* __restrict__ gates, int* __restrict__ counts) {
  __shared__ float smem[En * Dn];  // 32 KB
  __shared__ int lcnt[En];
  int bid = blockIdx.x;
  int t = threadIdx.x;

  if (bid < NB_G) {
    float* wgs = smem;
    for (int i = t; i < Dn * En; i += 256) {
      int d = i >> 3, e = i & 7;
      wgs[e * Dn + d] = wg[i];  // wg is [d][e]
    }
    if (t < En) lcnt[t] = 0;
    __syncthreads();
    int w = t >> 6, lane = t & 63;
#pragma unroll
    for (int r = 0; r < 2; r++) {
      int b = bid * 8 + w * 2 + r;
      const float* xr = x + (size_t)b * Dn;
      ushort_t* xo = x_bf + (size_t)b * Dn;
      float xv[16];
#pragma unroll
      for (int j = 0; j < 16; j++) xv[j] = xr[lane + j * 64];
      float acc[En];
#pragma unroll
      for (int e = 0; e < En; e++) acc[e] = 0.f;
#pragma unroll
      for (int j = 0; j < 16; j++) {
        int d = lane + j * 64;
        xo[d] = f2bf(xv[j]);
#pragma unroll
        for (int e = 0; e < En; e++) acc[e] += xv[j] * wgs[e * Dn + d];
      }
#pragma unroll
      for (int off = 32; off; off >>= 1) {
#pragma unroll
        for (int e = 0; e < En; e++) acc[e] += __shfl_down(acc[e], off);
      }
      if (lane == 0) {
        float best = -1e30f, second = -1e30f; int bi = 0, si = 0;
#pragma unroll
        for (int e = 0; e < En; e++) {
          float l = acc[e];
          if (l > best) { second = best; si = bi; best = l; bi = e; }
          else if (l > second) { second = l; si = e; }
        }
        float e1 = expf(second - best);
        float inv = 1.f / (1.f + e1);
        top_idx[2 * b] = bi; top_idx[2 * b + 1] = si;
        gates[2 * b] = inv;  gates[2 * b + 1] = e1 * inv;
        atomicAdd(&lcnt[bi], 1);
        atomicAdd(&lcnt[si], 1);
      }
    }
    __syncthreads();
    if (t < En) {
      int c = lcnt[t];
      if (c) atomicAdd(&counts[t], c);
    }
  } else if (bid < NB_G + NB_T1) {
    int idx = bid - NB_G;
    constexpr int TPE = (Dn / 64) * (Hn / 64);
    int z = idx / TPE, rem = idx % TPE;
    int r0 = (rem / (Hn / 64)) * 64, c0 = (rem % (Hn / 64)) * 64;
    tcast64(fc1w + (size_t)z * Dn * Hn, w1t + (size_t)z * Dn * Hn, Dn, Hn, r0, c0, smem);
  } else {
    int idx = bid - NB_G - NB_T1;
    constexpr int TPE = (Hn / 64) * (On / 64);
    int z = idx / TPE, rem = idx % TPE;
    int r0 = (rem / (On / 64)) * 64, c0 = (rem % (On / 64)) * 64;
    tcast64(fc2w + (size_t)z * Hn * On, w2t + (size_t)z * Hn * On, Hn, On, r0, c0, smem);
  }
}

// ---------------- offsets (exclusive prefix over 8 counts) ----------------
__global__ void offsets_kernel(const int* counts, int* offsets, int* cursors) {
  if (threadIdx.x == 0) {
    int s = 0;
    for (int e = 0; e < En; e++) { offsets[e] = s; s += counts[e]; }
  }
  if (threadIdx.x < En) cursors[threadIdx.x] = 0;
}

// ---------------- assign rows to compact slots ----------------
__global__ void assign_kernel(const int* __restrict__ top_idx, const int* __restrict__ offsets,
                              int* cursors, int* __restrict__ s2r, int* __restrict__ r2s) {
  int b = blockIdx.x * 256 + threadIdx.x;
  if (b >= Bn) return;
#pragma unroll
  for (int k = 0; k < 2; k++) {
    int e = top_idx[2 * b + k];
    int pos = atomicAdd(&cursors[e], 1);
    int slot = offsets[e] + pos;
    s2r[slot] = b;
    r2s[2 * b + k] = slot;
  }
}

// ---- grouped GEMM: 64x64xBK64 tile, 4 waves (2Mx2N), mfma 16x16x32 bf16 (r9 structure) ----
// 16 KB LDS single-buffer, 8 blocks/CU, T2 swizzle.
// NEW: 1D grid with expert = blockIdx.x % 8 -> dispatch round-robin pins expert to XCD
// (8 experts x 8 XCDs): one expert's weights (4MB fc1 / 2MB fc2) stay resident in its
// XCD's private L2 instead of 8 experts thrashing every L2.
template <bool GATHER, bool FC1, int N, int K, int SPLITK, int RBMAX>
__global__ __launch_bounds__(256, 8) void moe_gemm_kernel(
    const ushort_t* __restrict__ A, const ushort_t* __restrict__ WT,
    const float* __restrict__ bias, const int* __restrict__ offsets,
    const int* __restrict__ counts, const int* __restrict__ s2r,
    ushort_t* __restrict__ outH, float* __restrict__ outL, float* __restrict__ outL2) {
  constexpr int NBL = N / 64;
  constexpr int KS = K / SPLITK;
  constexpr int NT = KS / 64;
  int bx = blockIdx.x;
  int e = bx % En;           // expert pinned to XCD (bx%8 -> XCD round-robin)
  int r = bx / En;
  int rb = r % RBMAX;
  int q = r / RBMAX;
  int nb = (q % NBL) * 64;
  int ks = q / NBL;
  int cnt = counts[e];
  if (rb * 64 >= cnt) return;
  int base = offsets[e];
  int k0 = ks * KS;
  __shared__ __align__(16) ushort_t As[64 * 64];  // 8 KB
  __shared__ __align__(16) ushort_t Bs[64 * 64];  // 8 KB
  int t = threadIdx.x;
  int lane = t & 63, w = t >> 6;
  int wr = w >> 1, wc = w & 1;

  int srow = t >> 3;                       // staging row within each 32-row group
  int scol = ((t & 7) ^ (srow & 7)) * 8;   // pre-swizzled global column (elements)

  const ushort_t* aptr[2];
#pragma unroll
  for (int i = 0; i < 2; i++) {
    int lr = rb * 64 + i * 32 + srow;
    int lrc = lr < cnt ? lr : cnt - 1;
    int slot = base + lrc;
    int row = GATHER ? s2r[slot] : slot;
    aptr[i] = A + (size_t)row * K + k0 + scol;
  }
  const ushort_t* bptr = WT + ((size_t)e * N + nb + srow) * K + k0 + scol;

  f32x4 zero = {0.f, 0.f, 0.f, 0.f};
  f32x4 acc[2][2];
#pragma unroll
  for (int m = 0; m < 2; m++)
#pragma unroll
    for (int n = 0; n < 2; n++) acc[m][n] = zero;

  int a_r = wr * 32 + (lane & 15);   // A fragment row base (wave rows: wr*32..+31)
  int b_r = wc * 32 + (lane & 15);   // B fragment row base (wave cols: wc*32..+31)
  int axor = lane & 7;               // row&7 (row bases mult of 8 -> invariant)
  int c16 = lane >> 4;               // base 16B-slot index within row

  for (int kt = 0; kt < NT; kt++) {
#pragma unroll
    for (int i = 0; i < 2; i++) gload16(aptr[i] + kt * 64, &As[i * 2048 + t * 8]);
#pragma unroll
    for (int i = 0; i < 2; i++)
      gload16(bptr + (size_t)i * 32 * K + kt * 64, &Bs[i * 2048 + t * 8]);
    __syncthreads();  // drains vmcnt before LDS reads
#pragma unroll
    for (int kk = 0; kk < 2; kk++) {
      bf16x8 af[2], bfr[2];
#pragma unroll
      for (int m = 0; m < 2; m++)
        af[m] = *(const bf16x8*)((const char*)As + (a_r + m * 16) * 128 +
                                 (((kk * 4 + c16) ^ axor) << 4));
#pragma unroll
      for (int n = 0; n < 2; n++)
        bfr[n] = *(const bf16x8*)((const char*)Bs + (b_r + n * 16) * 128 +
                                  (((kk * 4 + c16) ^ axor) << 4));
#pragma unroll
      for (int m = 0; m < 2; m++)
#pragma unroll
        for (int n = 0; n < 2; n++)
          acc[m][n] = __builtin_amdgcn_mfma_f32_16x16x32_bf16(af[m], bfr[n], acc[m][n], 0, 0, 0);
    }
    __syncthreads();  // protect LDS before next stage
  }

  // epilogue: D layout col=lane&15, row=(lane>>4)*4+i
  float* dst = (SPLITK > 1 && ks > 0) ? (outL2 + (size_t)(ks - 1) * (2 * Bn * On)) : outL;
  int lr0 = rb * 64 + wr * 32;
#pragma unroll
  for (int m = 0; m < 2; m++) {
#pragma unroll
    for (int i = 0; i < 4; i++) {
      int lr = lr0 + m * 16 + (lane >> 4) * 4 + i;
      if (lr < cnt) {
        int slot = base + lr;
#pragma unroll
        for (int n = 0; n < 2; n++) {
          int col = nb + wc * 32 + n * 16 + (lane & 15);
          float v = acc[m][n][i] + (ks == 0 ? bias[e * N + col] : 0.f);
          if (FC1) {
            float g = 0.5f * v * (1.0f + erff(v * 0.70710678118654752f));
            outH[(size_t)slot * N + col] = f2bf(g);
          } else {
            dst[(size_t)slot * N + col] = v;
          }
        }
      }
    }
  }
}

// ---------------- combine: sum split-K partials, logsoftmax over O=512, weighted sum ----------------
__device__ __forceinline__ float blk_reduce(float v, bool ismax) {
  __shared__ float sbuf[4];
  int lane = threadIdx.x & 63, w = threadIdx.x >> 6;
#pragma unroll
  for (int off = 32; off; off >>= 1) {
    float o = __shfl_down(v, off);
    v = ismax ? fmaxf(v, o) : (v + o);
  }
  __syncthreads();
  if (lane == 0) sbuf[w] = v;
  __syncthreads();
  float r = sbuf[0];
#pragma unroll
  for (int i = 1; i < 4; i++) r = ismax ? fmaxf(r, sbuf[i]) : (r + sbuf[i]);
  return r;
}

__global__ void combine_kernel(const float* __restrict__ l2a, const float* __restrict__ l2b,
                               const int* __restrict__ r2s, const float* __restrict__ gates,
                               float* __restrict__ out) {
  int b = blockIdx.x, t = threadIdx.x;
  float c0 = 0.f, c1 = 0.f;
#pragma unroll
  for (int k = 0; k < 2; k++) {
    int slot = r2s[2 * b + k];
    float g = gates[2 * b + k];
    const float* lp0 = l2a + (size_t)slot * On;
    float v0 = lp0[t], v1 = lp0[t + 256];
#pragma unroll
    for (int p = 0; p < 3; p++) {
      const float* lpp = l2b + (size_t)p * (2 * Bn * On) + (size_t)slot * On;
      v0 += lpp[t];
      v1 += lpp[t + 256];
    }
    float m = blk_reduce(fmaxf(v0, v1), true);
    float s = blk_reduce(expf(v0 - m) + expf(v1 - m), false);
    float lse = m + logf(s);
    c0 += g * expf(v0 - lse);
    c1 += g * expf(v1 - lse);
  }
  const float EPSv = 2.220446049250313e-16f;
  out[(size_t)b * On + t] = logf(fmaxf(c0, EPSv));
  out[(size_t)b * On + t + 256] = logf(fmaxf(c1, EPSv));
}

extern "C" void kernel_launch(void* const* d_in, const int* in_sizes, int n_in,
                              void* d_out, int out_size, void* d_ws, size_t ws_size,
                              hipStream_t stream) {
  const float* x = (const float*)d_in[0];
  const float* wgate = (const float*)d_in[1];
  const float* fc1w = (const float*)d_in[2];
  const float* fc1b = (const float*)d_in[3];
  const float* fc2w = (const float*)d_in[4];
  const float* fc2b = (const float*)d_in[5];
  float* out = (float*)d_out;

  char* ws = (char*)d_ws;
  size_t o = 0;
  ushort_t* x_bf = (ushort_t*)(ws + o); o += (size_t)Bn * Dn * 2;        // 4 MB
  ushort_t* w1t  = (ushort_t*)(ws + o); o += (size_t)En * Hn * Dn * 2;   // 32 MB [E][H][D]
  ushort_t* w2t  = (ushort_t*)(ws + o); o += (size_t)En * On * Hn * 2;   // 16 MB [E][O][H]
  ushort_t* hbuf = (ushort_t*)(ws + o); o += (size_t)2 * Bn * Hn * 2;    // 16 MB [slot][H]
  float* l2buf   = (float*)(ws + o);    o += (size_t)2 * Bn * On * 4;    // 8 MB (split-K partial 0)
  int* top_idx   = (int*)(ws + o);      o += (size_t)Bn * 2 * 4;
  float* gates   = (float*)(ws + o);    o += (size_t)Bn * 2 * 4;
  int* r2s       = (int*)(ws + o);      o += (size_t)Bn * 2 * 4;
  int* s2r       = (int*)(ws + o);      o += (size_t)2 * Bn * 4;
  int* counts    = (int*)(ws + o);      o += 64;
  int* offsets   = (int*)(ws + o);      o += 64;
  int* cursors   = (int*)(ws + o);      o += 64;
  // split-K partials 1..3 (24 MB) alias w1t (32 MB): w1t is fully consumed by fc1
  // (completes before fc2 starts, same stream) and rewritten by prep each launch.
  float* l2buf1  = (float*)w1t;

  hipLaunchKernelGGL(init_kernel, dim3(1), dim3(64), 0, stream, counts, cursors);
  hipLaunchKernelGGL(prep_kernel, dim3(NB_G + NB_T1 + NB_T2), dim3(256), 0, stream,
                     x, wgate, fc1w, fc2w, x_bf, w1t, w2t, top_idx, gates, counts);
  hipLaunchKernelGGL(offsets_kernel, dim3(1), dim3(64), 0, stream, counts, offsets, cursors);
  hipLaunchKernelGGL(assign_kernel, dim3(Bn / 256), dim3(256), 0, stream,
                     top_idx, offsets, cursors, s2r, r2s);
  // fc1: 1D grid = RBMAX(32) * NBL(32) * SPLITK(1) * En(8) = 8192
  hipLaunchKernelGGL((moe_gemm_kernel<true, true, Hn, Dn, 1, 32>), dim3(32 * 32 * 8), dim3(256),
                     0, stream, x_bf, w1t, fc1b, offsets, counts, s2r, hbuf, (float*)nullptr,
                     (float*)nullptr);
  // fc2: 1D grid = RBMAX(32) * NBL(8) * SPLITK(4) * En(8) = 8192
  hipLaunchKernelGGL((moe_gemm_kernel<false, false, On, Hn, 4, 32>), dim3(32 * 8 * 4 * 8),
                     dim3(256), 0, stream, hbuf, w2t, fc2b, offsets, counts, s2r,
                     (ushort_t*)nullptr, l2buf, l2buf1);
  hipLaunchKernelGGL(combine_kernel, dim3(Bn), dim3(256), 0, stream, l2buf, l2buf1, r2s, gates, out);
}